// Round 1
// baseline (687.772 us; speedup 1.0000x reference)
//
#include <hip/hip_runtime.h>
#include <math.h>

#define BB 8
#define SS 4096
#define HH 4096
#define DD 128
#define NMAX 64

// ---------------- Kernel A: sentinel scan ----------------
// grid: (BB), block: 64 (one wave per batch)
__global__ void scan_kernel(const int* __restrict__ mask,
                            int* __restrict__ sent_pos,
                            int* __restrict__ count) {
    int b = blockIdx.x;
    int lane = threadIdx.x;  // 0..63
    int running = 0;
    const int* mrow = mask + (size_t)b * SS;
    for (int base = 0; base < SS; base += 64) {
        int m = (mrow[base + lane] > 0) ? 1 : 0;
        unsigned long long bal = __ballot(m);
        if (m) {
            int r = running + __popcll(bal & ((1ull << lane) - 1ull));
            if (r < NMAX) sent_pos[b * NMAX + r] = base + lane;
        }
        running += __popcll(bal);
    }
    if (lane == 0) count[b] = running > NMAX ? NMAX : running;
}

// ---------------- Kernel B: gathered projections ----------------
// grid: (NMAX+1, BB), block: 256
// blockIdx.x == NMAX -> q row (position SS-1, proj Wq)
// blockIdx.x <  NMAX -> k row j (if j < count), proj Wk, plus v = x.Wr
__global__ void proj_kernel(const float* __restrict__ hs,
                            const float* __restrict__ Wq, const float* __restrict__ bq,
                            const float* __restrict__ Wk, const float* __restrict__ bk,
                            const float* __restrict__ Wr, const float* __restrict__ br,
                            const int* __restrict__ sent_pos, const int* __restrict__ count,
                            float* __restrict__ qrow,   // [BB][DD]
                            float* __restrict__ krows,  // [BB][NMAX][DD]
                            float* __restrict__ vs) {   // [BB][NMAX]
    int b = blockIdx.y;
    int j = blockIdx.x;
    int tid = threadIdx.x;
    bool is_q = (j == NMAX);
    int cnt = count[b];
    if (!is_q && j >= cnt) return;

    int row = is_q ? (SS - 1) : sent_pos[b * NMAX + j];
    const float* x = hs + ((size_t)b * SS + (size_t)row) * HH;

    __shared__ float xs[HH];           // 16 KB
    __shared__ float4 red[256];        // 4 KB
    __shared__ float vred[256];        // 1 KB

    // stage hidden row into LDS (float4, coalesced)
    for (int i = tid; i < HH / 4; i += 256)
        ((float4*)xs)[i] = ((const float4*)x)[i];
    __syncthreads();

    const float* W = is_q ? Wq : Wk;
    const float* bias = is_q ? bq : bk;

    // thread t: 4 output dims d0..d0+3, 1/8 of the H range
    int d0 = (tid & 31) * 4;
    int h0 = (tid >> 5) * (HH / 8);
    const float* Wp = W + (size_t)h0 * DD + d0;
    float4 acc = make_float4(0.f, 0.f, 0.f, 0.f);
#pragma unroll 4
    for (int h = 0; h < HH / 8; ++h) {
        float xv = xs[h0 + h];
        float4 w = *(const float4*)Wp;
        Wp += DD;
        acc.x += xv * w.x;
        acc.y += xv * w.y;
        acc.z += xv * w.z;
        acc.w += xv * w.w;
    }
    red[tid] = acc;
    __syncthreads();

    if (tid < 32) {
        float4 s = red[tid];
#pragma unroll
        for (int p = 1; p < 8; ++p) {
            float4 o = red[tid + p * 32];
            s.x += o.x; s.y += o.y; s.z += o.z; s.w += o.w;
        }
        int dd = tid * 4;
        float* outp = is_q ? (qrow + b * DD) : (krows + ((size_t)b * NMAX + j) * DD);
        outp[dd + 0] = s.x + bias[dd + 0];
        outp[dd + 1] = s.y + bias[dd + 1];
        outp[dd + 2] = s.z + bias[dd + 2];
        outp[dd + 3] = s.w + bias[dd + 3];
    }

    if (!is_q) {
        float pv = 0.f;
        for (int h = tid; h < HH; h += 256) pv += xs[h] * Wr[h];
        vred[tid] = pv;
        __syncthreads();
        for (int s = 128; s > 0; s >>= 1) {
            if (tid < s) vred[tid] += vred[tid + s];
            __syncthreads();
        }
        if (tid == 0) vs[b * NMAX + j] = vred[0] + br[0];
    }
}

// ---------------- Kernel C: rope + softmax + rewards + loss ----------------
// grid: 1 block, 512 threads (8 waves; wave b = batch b, lane n = sentinel n)
__global__ void finalize_kernel(const float* __restrict__ qrow,
                                const float* __restrict__ krows,
                                const float* __restrict__ vs,
                                const int* __restrict__ count,
                                float* __restrict__ out) {  // [1 + BB]
    __shared__ float sfreq[64];
    __shared__ float qr[BB][DD];
    __shared__ float rew[BB];

    int tid = threadIdx.x;
    if (tid < 64) sfreq[tid] = powf(10000.f, -(float)tid / 64.f);
    __syncthreads();

    int b = tid >> 6;
    int l = tid & 63;
    int cnt = count[b];

    // rope q at rank cnt-1 (same wave writes+reads qr[b] -> lockstep safe)
    {
        float2 qp = ((const float2*)(qrow + b * DD))[l];
        float s, c;
        sincosf((float)(cnt - 1) * sfreq[l], &s, &c);
        qr[b][2 * l]     = qp.x * c - qp.y * s;
        qr[b][2 * l + 1] = qp.x * s + qp.y * c;
    }
    __syncthreads();

    float lg = -INFINITY;
    if (l < cnt) {
        const float2* kp = (const float2*)(krows + ((size_t)b * NMAX + l) * DD);
        float acc = 0.f;
#pragma unroll 8
        for (int i = 0; i < 64; ++i) {
            float2 kv = kp[i];
            float s, c;
            sincosf((float)l * sfreq[i], &s, &c);
            float kr0 = kv.x * c - kv.y * s;
            float kr1 = kv.x * s + kv.y * c;
            acc += qr[b][2 * i] * kr0 + qr[b][2 * i + 1] * kr1;
        }
        lg = acc * 0.08838834764831845f;  // 1/sqrt(128)
    }

    // wave-wide softmax over 64 lanes
    float m = lg;
#pragma unroll
    for (int off = 32; off > 0; off >>= 1) m = fmaxf(m, __shfl_xor(m, off));
    float e = expf(lg - m);  // -inf lanes -> 0
    float sum = e;
#pragma unroll
    for (int off = 32; off > 0; off >>= 1) sum += __shfl_xor(sum, off);
    float attn = e / sum;

    float vn = 0.f, vp = 0.f;
    if (l < cnt) {
        vn = vs[b * NMAX + l];
        if (l > 0) vp = vs[b * NMAX + l - 1];
    }
    float r = attn * (vn - vp);
#pragma unroll
    for (int off = 32; off > 0; off >>= 1) r += __shfl_xor(r, off);

    if (l == 0) {
        rew[b] = r;
        out[1 + b] = r;
    }
    __syncthreads();

    if (tid == 0) {
        float L = 0.f;
        for (int i = 0; i < BB / 2; ++i) {
            float z = rew[i] - rew[i + BB / 2];
            // -log_sigmoid(z) = max(-z,0) + log1p(exp(-|z|))
            L += fmaxf(-z, 0.f) + log1pf(expf(-fabsf(z)));
        }
        out[0] = L / (float)(BB / 2);
    }
}

extern "C" void kernel_launch(void* const* d_in, const int* in_sizes, int n_in,
                              void* d_out, int out_size, void* d_ws, size_t ws_size,
                              hipStream_t stream) {
    const float* hs  = (const float*)d_in[0];
    const int*   msk = (const int*)d_in[1];
    const float* Wq  = (const float*)d_in[2];
    const float* bq  = (const float*)d_in[3];
    const float* Wk  = (const float*)d_in[4];
    const float* bk  = (const float*)d_in[5];
    const float* Wr  = (const float*)d_in[6];
    const float* br  = (const float*)d_in[7];
    float* out = (float*)d_out;

    // workspace layout
    int* sent_pos = (int*)d_ws;                       // 8*64 ints
    int* count    = sent_pos + BB * NMAX;             // 8 ints
    float* qrow   = (float*)(count + 8);              // 8*128 f  (16B-aligned: byte 2080)
    float* krows  = qrow + BB * DD;                   // 8*64*128 f
    float* vsbuf  = krows + (size_t)BB * NMAX * DD;   // 8*64 f

    scan_kernel<<<BB, 64, 0, stream>>>(msk, sent_pos, count);
    proj_kernel<<<dim3(NMAX + 1, BB), 256, 0, stream>>>(
        hs, Wq, bq, Wk, bk, Wr, br, sent_pos, count, qrow, krows, vsbuf);
    finalize_kernel<<<1, 512, 0, stream>>>(qrow, krows, vsbuf, count, out);
}

// Round 2
// 616.451 us; speedup vs baseline: 1.1157x; 1.1157x over previous
//
#include <hip/hip_runtime.h>
#include <math.h>

#define BB 8
#define SS 4096
#define HH 4096
#define DD 128
#define NMAX 64
#define RPB 8      // rows per proj block
#define HSL 1024   // H elements per proj block (4 slices cover HH)

// ---------------- Kernel A: sentinel scan + accumulator init ----------------
// grid: (BB), block: 256
__global__ void scan_kernel(const int* __restrict__ mask,
                            const float* __restrict__ bq,
                            const float* __restrict__ bk,
                            const float* __restrict__ br,
                            int* __restrict__ sent_pos,
                            int* __restrict__ count,
                            float* __restrict__ qrow,   // [BB][DD]
                            float* __restrict__ krows,  // [BB][NMAX][DD]
                            float* __restrict__ vs) {   // [BB][NMAX]
    int b = blockIdx.x;
    int t = threadIdx.x;

    // --- init accumulators with bias (proj atomically adds partials) ---
    for (int i = t; i < DD; i += 256) qrow[b * DD + i] = bq[i];
    for (int i = t; i < NMAX * DD; i += 256) krows[b * NMAX * DD + i] = bk[i & (DD - 1)];
    if (t < NMAX) vs[b * NMAX + t] = br[0];

    // --- scan: thread t owns positions [t*16, t*16+16) ---
    const int4* m4 = (const int4*)(mask + (size_t)b * SS);
    int vals[16];
    {
        int4 v0 = m4[t * 4 + 0], v1 = m4[t * 4 + 1], v2 = m4[t * 4 + 2], v3 = m4[t * 4 + 3];
        vals[0] = v0.x; vals[1] = v0.y; vals[2] = v0.z; vals[3] = v0.w;
        vals[4] = v1.x; vals[5] = v1.y; vals[6] = v1.z; vals[7] = v1.w;
        vals[8] = v2.x; vals[9] = v2.y; vals[10] = v2.z; vals[11] = v2.w;
        vals[12] = v3.x; vals[13] = v3.y; vals[14] = v3.z; vals[15] = v3.w;
    }
    int c = 0;
#pragma unroll
    for (int i = 0; i < 16; ++i) c += (vals[i] > 0) ? 1 : 0;

    __shared__ int sc[256];
    sc[t] = c;
    __syncthreads();
    for (int off = 1; off < 256; off <<= 1) {
        int add = (t >= off) ? sc[t - off] : 0;
        __syncthreads();
        sc[t] += add;
        __syncthreads();
    }
    int prefix = sc[t] - c;  // exclusive
    int total = sc[255];

    int r = prefix;
#pragma unroll
    for (int i = 0; i < 16; ++i) {
        if (vals[i] > 0) {
            if (r < NMAX) sent_pos[b * NMAX + r] = t * 16 + i;
            r++;
        }
    }
    if (t == 0) count[b] = total > NMAX ? NMAX : total;
}

// ---------------- Kernel B: gathered projections (split-H, row-tiled) ----------------
// grid: (9, BB, HH/HSL), block: 256
// blockIdx.x = row group g: g<8 -> k slots [8g, 8g+8); g==8 -> q row (slot 64)
__global__ void __launch_bounds__(256)
proj_kernel(const float* __restrict__ hs,
            const float* __restrict__ Wq,
            const float* __restrict__ Wk,
            const float* __restrict__ Wr,
            const int* __restrict__ sent_pos, const int* __restrict__ count,
            float* __restrict__ qrow,   // [BB][DD]  (pre-biased)
            float* __restrict__ krows,  // [BB][NMAX][DD]
            float* __restrict__ vs) {   // [BB][NMAX]
    int g = blockIdx.x;
    int b = blockIdx.y;
    int s = blockIdx.z;
    int t = threadIdx.x;
    int cnt = count[b];
    int slot0 = g * RPB;
    bool is_q_grp = (g == 8);
    if (!is_q_grp && slot0 >= cnt) return;

    int hoff = s * HSL;

    __shared__ float xs[RPB][HSL];   // 32 KB (reused as reduction buffer after loop)
    __shared__ float wsum[RPB][4];

    int wv = t >> 6;   // wave 0..3
    int lane = t & 63;

    // Wr slice (loop-invariant across rows)
    float4 wr = ((const float4*)(Wr + hoff))[t];

    // stage rows (zero invalid ones) + v partials
    for (int r = 0; r < RPB; ++r) {
        int slot = slot0 + r;
        bool valid = is_q_grp ? (r == 0) : (slot < cnt);
        int row = is_q_grp ? (SS - 1) : (valid ? sent_pos[b * NMAX + slot] : 0);
        float4 xv = make_float4(0.f, 0.f, 0.f, 0.f);
        if (valid) {
            const float4* xp = (const float4*)(hs + ((size_t)b * SS + (size_t)row) * HH + hoff);
            xv = xp[t];
        }
        ((float4*)xs[r])[t] = xv;
        if (!is_q_grp) {
            float d = xv.x * wr.x + xv.y * wr.y + xv.z * wr.z + xv.w * wr.w;
#pragma unroll
            for (int off = 32; off > 0; off >>= 1) d += __shfl_down(d, off);
            if (lane == 0) wsum[r][wv] = d;
        }
    }
    __syncthreads();

    // v atomic adds (k rows only)
    if (!is_q_grp && t < RPB) {
        int slot = slot0 + t;
        if (slot < cnt)
            atomicAdd(&vs[b * NMAX + slot], wsum[t][0] + wsum[t][1] + wsum[t][2] + wsum[t][3]);
    }

    // main loop: thread covers 4 d-dims x 128 h within the slice, all 8 rows
    const float* W = is_q_grp ? Wq : Wk;
    int lane_d = (t & 31) * 4;
    int hbase = (t >> 5) * (HSL / 8);   // 128 h per thread
    const float4* wp = (const float4*)(W + (size_t)(hoff + hbase) * DD + lane_d);
    float4 acc[RPB];
#pragma unroll
    for (int r = 0; r < RPB; ++r) acc[r] = make_float4(0.f, 0.f, 0.f, 0.f);

    for (int hl = 0; hl < HSL / 8; ++hl) {
        float4 w = *wp;
        wp += DD / 4;
#pragma unroll
        for (int r = 0; r < RPB; ++r) {
            float xv = xs[r][hbase + hl];
            acc[r].x += xv * w.x;
            acc[r].y += xv * w.y;
            acc[r].z += xv * w.z;
            acc[r].w += xv * w.w;
        }
    }
    __syncthreads();

    // reuse xs as reduction buffer: red[r][256] float4
    float4* red = (float4*)&xs[0][0];
#pragma unroll
    for (int r = 0; r < RPB; ++r) red[r * 256 + t] = acc[r];
    __syncthreads();

    // thread t: row r = t>>5, dims (t&31)*4 .. +3; sum 8 h-group partials
    {
        int r = t >> 5;
        int dl = t & 31;
        int slot = slot0 + r;
        bool valid = is_q_grp ? (r == 0) : (slot < cnt);
        if (valid) {
            float4 ssum = red[r * 256 + dl];
#pragma unroll
            for (int p = 1; p < 8; ++p) {
                float4 o = red[r * 256 + p * 32 + dl];
                ssum.x += o.x; ssum.y += o.y; ssum.z += o.z; ssum.w += o.w;
            }
            float* outp = is_q_grp ? (qrow + b * DD + dl * 4)
                                   : (krows + ((size_t)b * NMAX + slot) * DD + dl * 4);
            atomicAdd(outp + 0, ssum.x);
            atomicAdd(outp + 1, ssum.y);
            atomicAdd(outp + 2, ssum.z);
            atomicAdd(outp + 3, ssum.w);
        }
    }
}

// ---------------- Kernel C: rope + softmax + rewards + loss ----------------
// grid: 1 block, 512 threads (8 waves; wave b = batch b, lane n = sentinel n)
__global__ void finalize_kernel(const float* __restrict__ qrow,
                                const float* __restrict__ krows,
                                const float* __restrict__ vs,
                                const int* __restrict__ count,
                                float* __restrict__ out) {  // [1 + BB]
    __shared__ float sfreq[64];
    __shared__ float qr[BB][DD];
    __shared__ float rew[BB];

    int tid = threadIdx.x;
    if (tid < 64) sfreq[tid] = powf(10000.f, -(float)tid / 64.f);
    __syncthreads();

    int b = tid >> 6;
    int l = tid & 63;
    int cnt = count[b];

    // rope q at rank cnt-1 (same wave writes+reads qr[b] -> lockstep safe)
    {
        float2 qp = ((const float2*)(qrow + b * DD))[l];
        float s, c;
        sincosf((float)(cnt - 1) * sfreq[l], &s, &c);
        qr[b][2 * l]     = qp.x * c - qp.y * s;
        qr[b][2 * l + 1] = qp.x * s + qp.y * c;
    }
    __syncthreads();

    float lg = -INFINITY;
    if (l < cnt) {
        const float2* kp = (const float2*)(krows + ((size_t)b * NMAX + l) * DD);
        float acc = 0.f;
#pragma unroll 8
        for (int i = 0; i < 64; ++i) {
            float2 kv = kp[i];
            float s, c;
            sincosf((float)l * sfreq[i], &s, &c);
            float kr0 = kv.x * c - kv.y * s;
            float kr1 = kv.x * s + kv.y * c;
            acc += qr[b][2 * i] * kr0 + qr[b][2 * i + 1] * kr1;
        }
        lg = acc * 0.08838834764831845f;  // 1/sqrt(128)
    }

    // wave-wide softmax over 64 lanes
    float m = lg;
#pragma unroll
    for (int off = 32; off > 0; off >>= 1) m = fmaxf(m, __shfl_xor(m, off));
    float e = expf(lg - m);  // -inf lanes -> 0
    float sum = e;
#pragma unroll
    for (int off = 32; off > 0; off >>= 1) sum += __shfl_xor(sum, off);
    float attn = e / sum;

    float vn = 0.f, vp = 0.f;
    if (l < cnt) {
        vn = vs[b * NMAX + l];
        if (l > 0) vp = vs[b * NMAX + l - 1];
    }
    float r = attn * (vn - vp);
#pragma unroll
    for (int off = 32; off > 0; off >>= 1) r += __shfl_xor(r, off);

    if (l == 0) {
        rew[b] = r;
        out[1 + b] = r;
    }
    __syncthreads();

    if (tid == 0) {
        float L = 0.f;
        for (int i = 0; i < BB / 2; ++i) {
            float z = rew[i] - rew[i + BB / 2];
            // -log_sigmoid(z) = max(-z,0) + log1p(exp(-|z|))
            L += fmaxf(-z, 0.f) + log1pf(expf(-fabsf(z)));
        }
        out[0] = L / (float)(BB / 2);
    }
}

extern "C" void kernel_launch(void* const* d_in, const int* in_sizes, int n_in,
                              void* d_out, int out_size, void* d_ws, size_t ws_size,
                              hipStream_t stream) {
    const float* hs  = (const float*)d_in[0];
    const int*   msk = (const int*)d_in[1];
    const float* Wq  = (const float*)d_in[2];
    const float* bq  = (const float*)d_in[3];
    const float* Wk  = (const float*)d_in[4];
    const float* bk  = (const float*)d_in[5];
    const float* Wr  = (const float*)d_in[6];
    const float* br  = (const float*)d_in[7];
    float* out = (float*)d_out;

    // workspace layout
    int* sent_pos = (int*)d_ws;                       // 8*64 ints
    int* count    = sent_pos + BB * NMAX;             // 8 ints
    float* qrow   = (float*)(count + 8);              // 8*128 f  (16B-aligned: byte 2080)
    float* krows  = qrow + BB * DD;                   // 8*64*128 f
    float* vsbuf  = krows + (size_t)BB * NMAX * DD;   // 8*64 f

    scan_kernel<<<BB, 256, 0, stream>>>(msk, bq, bk, br, sent_pos, count, qrow, krows, vsbuf);
    proj_kernel<<<dim3(9, BB, HH / HSL), 256, 0, stream>>>(
        hs, Wq, Wk, Wr, sent_pos, count, qrow, krows, vsbuf);
    finalize_kernel<<<1, 512, 0, stream>>>(qrow, krows, vsbuf, count, out);
}